// Round 5
// baseline (166.284 us; speedup 1.0000x reference)
//
#include <hip/hip_runtime.h>
#include <hip/hip_bf16.h>

// B=2, S=2048, D=1024, H=16, HD=64. fp32 in, fp32 out, bf16-tolerance threshold.
// Pipeline: convert->bf16 | QKV GEMM (mfma, fused bias+RoPE) | V-transpose |
//           flash attn (k-split x2, fixed-max softmax) | combine | out GEMM.

typedef unsigned short u16;
typedef short bf16x8 __attribute__((ext_vector_type(8)));
typedef float f32x4 __attribute__((ext_vector_type(4)));

__device__ __forceinline__ u16 f2bf(float f) {
    unsigned u = __builtin_bit_cast(unsigned, f);
    u += 0x7fffu + ((u >> 16) & 1u);   // RNE
    return (u16)(u >> 16);
}
__device__ __forceinline__ float bf2f(u16 h) {
    unsigned u = ((unsigned)h) << 16;
    return __builtin_bit_cast(float, u);
}

// ---------------- fp32 -> bf16 convert (4 elems/thread, exact grid) ----------------
__global__ __launch_bounds__(256) void f32_to_bf16_k(const float* __restrict__ in,
                                                     u16* __restrict__ out) {
    int i = (blockIdx.x * 256 + threadIdx.x) * 4;
    float4 v = *(const float4*)(in + i);
    uint2 o;
    o.x = (unsigned)f2bf(v.x) | ((unsigned)f2bf(v.y) << 16);
    o.y = (unsigned)f2bf(v.z) | ((unsigned)f2bf(v.w) << 16);
    *(uint2*)(out + i) = o;
}

// ---------------- bf16 GEMM: C[m][n] = sum_k A[m][k]*Bw[n][k] ----------------------
// EPI==0: bf16 out, 3-segment bias (bq|bk|bv), fused RoPE on cols < 2048.
// EPI==1: fp32 out, bias0 only, no RoPE.
template <int EPI>
__global__ __launch_bounds__(256) void gemm_bt(const u16* __restrict__ A,
                                               const u16* __restrict__ Bw,
                                               const float* __restrict__ bias0,
                                               const float* __restrict__ bias1,
                                               const float* __restrict__ bias2,
                                               const int* __restrict__ days,
                                               u16* __restrict__ outB,
                                               float* __restrict__ outF,
                                               int M, int N, int K) {
    __shared__ __align__(16) u16 As[128 * 32];
    __shared__ __align__(16) u16 Bs[128 * 32];
    const int tid = threadIdx.x;
    const int lane = tid & 63;
    const int w = tid >> 6;
    const int wr = w >> 1, wc = w & 1;
    const int lr = lane & 15, lg = lane >> 4;
    const int nbn = N >> 7;
    const int m0 = (blockIdx.x / nbn) << 7;
    const int n0 = (blockIdx.x % nbn) << 7;

    f32x4 acc[4][4] = {};

    const u16* aptr[2];
    const u16* bptr[2];
    int ldsoff[2];
#pragma unroll
    for (int i = 0; i < 2; ++i) {
        int c = (w * 2 + i) * 64 + lane;
        int row = c >> 2, kc = (c & 3) << 3;
        aptr[i] = A + (size_t)(m0 + row) * K + kc;
        bptr[i] = Bw + (size_t)(n0 + row) * K + kc;
        ldsoff[i] = (w * 2 + i) * 512;
    }

    for (int k0 = 0; k0 < K; k0 += 32) {
#pragma unroll
        for (int i = 0; i < 2; ++i) {
            __builtin_amdgcn_global_load_lds(
                (const __attribute__((address_space(1))) void*)(aptr[i] + k0),
                (__attribute__((address_space(3))) void*)(As + ldsoff[i]), 16, 0, 0);
            __builtin_amdgcn_global_load_lds(
                (const __attribute__((address_space(1))) void*)(bptr[i] + k0),
                (__attribute__((address_space(3))) void*)(Bs + ldsoff[i]), 16, 0, 0);
        }
        __syncthreads();
        bf16x8 af[4], bfr[4];
#pragma unroll
        for (int i = 0; i < 4; ++i)
            af[i] = *(const bf16x8*)(As + (wr * 64 + i * 16 + lr) * 32 + lg * 8);
#pragma unroll
        for (int j = 0; j < 4; ++j)
            bfr[j] = *(const bf16x8*)(Bs + (wc * 64 + j * 16 + lr) * 32 + lg * 8);
#pragma unroll
        for (int i = 0; i < 4; ++i)
#pragma unroll
            for (int j = 0; j < 4; ++j)
                acc[i][j] = __builtin_amdgcn_mfma_f32_16x16x32_bf16(af[i], bfr[j],
                                                                    acc[i][j], 0, 0, 0);
        __syncthreads();
    }

    auto bsel = [&](int ng) -> float {
        if (EPI != 0) return bias0[ng];
        return (ng < 1024) ? bias0[ng] : (ng < 2048) ? bias1[ng - 1024] : bias2[ng - 2048];
    };

    if (EPI == 0 && (n0 + wc * 64) < 2048) {
        // q/k region: wave's 64 cols = one full head; pairs (j, j+2) hold (x1, x2).
        const float C1 = -0.41524101186091903f;  // -log2(10000)/32
        const float inv0 = exp2f((float)lr * C1);
        const float inv1 = exp2f((float)(16 + lr) * C1);
#pragma unroll
        for (int i = 0; i < 4; ++i) {
            int mg = m0 + wr * 64 + i * 16 + lg * 4;
#pragma unroll
            for (int r = 0; r < 4; ++r) {
                int m = mg + r;
                int d = days[m];
                int ad = d < 0 ? -d : d;
                ad = ad > 2047 ? 2047 : ad;
                float pos = (float)ad;
#pragma unroll
                for (int j = 0; j < 2; ++j) {
                    int ng1 = n0 + wc * 64 + j * 16 + lr;
                    int ng2 = ng1 + 32;
                    float x1 = acc[i][j][r] + bsel(ng1);
                    float x2 = acc[i][j + 2][r] + bsel(ng2);
                    float ang = pos * (j ? inv1 : inv0);
                    float sn, cs;
                    __sincosf(ang, &sn, &cs);
                    outB[(size_t)m * N + ng1] = f2bf(x1 * cs - x2 * sn);
                    outB[(size_t)m * N + ng2] = f2bf(x2 * cs + x1 * sn);
                }
            }
        }
    } else {
#pragma unroll
        for (int i = 0; i < 4; ++i) {
            int mg = m0 + wr * 64 + i * 16 + lg * 4;
#pragma unroll
            for (int j = 0; j < 4; ++j) {
                int ng = n0 + wc * 64 + j * 16 + lr;
                float bias = bsel(ng);
#pragma unroll
                for (int r = 0; r < 4; ++r) {
                    float v = acc[i][j][r] + bias;
                    if (EPI == 0)
                        outB[(size_t)(mg + r) * N + ng] = f2bf(v);
                    else
                        outF[(size_t)(mg + r) * N + ng] = v;
                }
            }
        }
    }
}

// ---------------- V transpose: qkv v-region -> Vt[b,h,hd,s] ------------------------
__global__ __launch_bounds__(256) void v_transpose_k(const u16* __restrict__ qkv,
                                                     u16* __restrict__ vt) {
    __shared__ u16 tile[64][66];
    int st = blockIdx.x & 31;
    int bh = blockIdx.x >> 5;
    int b = bh >> 4, h = bh & 15;
    int s0 = st * 64;
    int t = threadIdx.x;
#pragma unroll
    for (int it = 0; it < 16; ++it) {
        int idx = it * 256 + t;
        int sr = idx >> 6, c = idx & 63;
        tile[sr][c] = qkv[(size_t)(b * 2048 + s0 + sr) * 3072 + 2048 + h * 64 + c];
    }
    __syncthreads();
#pragma unroll
    for (int it = 0; it < 16; ++it) {
        int idx = it * 256 + t;
        int hd = idx >> 6, sc = idx & 63;
        vt[((size_t)(bh * 64 + hd)) * 2048 + s0 + sc] = tile[sc][hd];
    }
}

// ---------------- flash attention v4 -----------------------------------------------
// Balanced causal pairing (block pair j handles q-tiles {j, 31-j}) + k-split across
// NS blocks by k-tile parity (fixed-max softmax => partials are additive: numerator
// and l just sum, no rescale). Swapped QK^T, lane-local softmax, exp2-folded decay,
// cvt_pk P-pack, LDS-staged K/V (both-sides XOR swizzle) double-buffered with
// counted vmcnt.

__device__ __forceinline__ void attn_tile(const u16* __restrict__ Ks,
                                          const u16* __restrict__ Vs,
                                          u16* __restrict__ Pw,
                                          const int* __restrict__ dbk,
                                          bf16x8 bq0, bf16x8 bq1, float dq_c, float c1,
                                          int qrel, bool domask,
                                          float& l_part, f32x4* acc, int lr, int lg) {
    f32x4 st_acc[4];
    __builtin_amdgcn_s_setprio(1);
#pragma unroll
    for (int st = 0; st < 4; ++st) {
        const int r2 = st * 16 + lr;
        const u16* kr = Ks + r2 * 64;
        bf16x8 ka0 = *(const bf16x8*)(kr + ((lg ^ (r2 & 7)) << 3));
        bf16x8 ka1 = *(const bf16x8*)(kr + (((4 + lg) ^ (r2 & 7)) << 3));
        f32x4 t = {};
        t = __builtin_amdgcn_mfma_f32_16x16x32_bf16(ka0, bq0, t, 0, 0, 0);
        t = __builtin_amdgcn_mfma_f32_16x16x32_bf16(ka1, bq1, t, 0, 0, 0);
        st_acc[st] = t;
    }
    __builtin_amdgcn_s_setprio(0);
    const float L2E = 1.4426950408889634f;
    const float POFF = 17.312340490667562f;  // 12*log2(e)
    float p[4][4];
#pragma unroll
    for (int st = 0; st < 4; ++st) {
        int4 dk4 = *(const int4*)(dbk + st * 16 + lg * 4);
#pragma unroll
        for (int r = 0; r < 4; ++r) {
            float dkf = (float)((&dk4.x)[r]);
            float dec = exp2f(__builtin_fmaf(dkf, c1, -dq_c));  // decay/8
            float v = st_acc[st][r] * dec;
            p[st][r] = exp2f(__builtin_fmaf(v, L2E, -POFF));
        }
    }
    if (domask) {
#pragma unroll
        for (int st = 0; st < 4; ++st)
#pragma unroll
            for (int r = 0; r < 4; ++r)
                p[st][r] = (st * 16 + lg * 4 + r <= qrel) ? p[st][r] : 0.f;
    }
#pragma unroll
    for (int st = 0; st < 4; ++st)
#pragma unroll
        for (int r = 0; r < 4; ++r) l_part += p[st][r];
#pragma unroll
    for (int st = 0; st < 4; ++st) {
        unsigned lo, hi;
        asm("v_cvt_pk_bf16_f32 %0, %1, %2" : "=v"(lo) : "v"(p[st][0]), "v"(p[st][1]));
        asm("v_cvt_pk_bf16_f32 %0, %1, %2" : "=v"(hi) : "v"(p[st][2]), "v"(p[st][3]));
        uint2 pk;
        pk.x = lo;
        pk.y = hi;
        int chunk = st * 2 + (lg >> 1);
        int idx = lr * 64 + ((chunk ^ (lr & 7)) << 3) + ((lg & 1) << 2);
        *(uint2*)&Pw[idx] = pk;
    }
    __builtin_amdgcn_s_setprio(1);
#pragma unroll
    for (int pv = 0; pv < 2; ++pv) {
        int chunk = pv * 4 + lg;
        bf16x8 pa = *(const bf16x8*)&Pw[lr * 64 + ((chunk ^ (lr & 7)) << 3)];
#pragma unroll
        for (int c = 0; c < 4; ++c) {
            const int r3 = c * 16 + lr;
            bf16x8 bv = *(const bf16x8*)(Vs + r3 * 64 + ((chunk ^ (r3 & 7)) << 3));
            acc[c] = __builtin_amdgcn_mfma_f32_16x16x32_bf16(pa, bv, acc[c], 0, 0, 0);
        }
    }
    __builtin_amdgcn_s_setprio(0);
}

template <int NS>
__global__ __launch_bounds__(256, NS == 2 ? 4 : 2) void attn_k(
    const u16* __restrict__ qkv, const u16* __restrict__ vt,
    const int* __restrict__ days, const float* __restrict__ decay_p,
    u16* __restrict__ outp, float* __restrict__ l_out) {
    __shared__ __align__(16) u16 Ks[2][4096];
    __shared__ __align__(16) u16 Vs[2][4096];
    __shared__ __align__(16) u16 Plds[4][1024];
    const int tid = threadIdx.x;
    const int lane = tid & 63;
    const int w = tid >> 6;
    const int lr = lane & 15, lg = lane >> 4;
    const int s = (NS == 2) ? (blockIdx.x & 1) : 0;
    const int j = (NS == 2) ? ((blockIdx.x >> 1) & 15) : (blockIdx.x & 15);
    const int bh = (NS == 2) ? (blockIdx.x >> 5) : (blockIdx.x >> 4);
    const int b = bh >> 4, h = bh & 15;
    const int qtB = 31 - j;
    const int qbA = j * 64 + w * 16;
    const int qbB = qtB * 64 + w * 16;
    const float rate = decay_p[0];
    const float c1 = rate * 1.4426950408889634f;

    const u16* qmat = qkv + (size_t)b * 2048 * 3072 + h * 64;
    const u16* kmat = qmat + 1024;
    const u16* vtm = vt + (size_t)bh * 64 * 2048;
    const int* db = days + b * 2048;

    const int cp0 = (w * 2 + 0) * 64 + lane;
    const int cp1 = (w * 2 + 1) * 64 + lane;
    const int r0 = cp0 >> 3, c0 = cp0 & 7;
    const int r1 = cp1 >> 3, c1i = cp1 & 7;
    const u16* ksrc0 = kmat + (size_t)r0 * 3072 + ((c0 ^ (r0 & 7)) << 3);
    const u16* ksrc1 = kmat + (size_t)r1 * 3072 + ((c1i ^ (r1 & 7)) << 3);
    const u16* vsrc0 = vtm + (size_t)r0 * 2048 + ((c0 ^ (r0 & 7)) << 3);
    const u16* vsrc1 = vtm + (size_t)r1 * 2048 + ((c1i ^ (r1 & 7)) << 3);
    const int doff0 = (w * 2 + 0) * 512;
    const int doff1 = (w * 2 + 1) * 512;

#define STAGE(T, BUF)                                                                  \
    do {                                                                               \
        __builtin_amdgcn_global_load_lds(                                              \
            (const __attribute__((address_space(1))) void*)(ksrc0 +                    \
                                                            (size_t)(T) * 64 * 3072), \
            (__attribute__((address_space(3))) void*)(&Ks[BUF][doff0]), 16, 0, 0);     \
        __builtin_amdgcn_global_load_lds(                                              \
            (const __attribute__((address_space(1))) void*)(ksrc1 +                    \
                                                            (size_t)(T) * 64 * 3072), \
            (__attribute__((address_space(3))) void*)(&Ks[BUF][doff1]), 16, 0, 0);     \
        __builtin_amdgcn_global_load_lds(                                              \
            (const __attribute__((address_space(1))) void*)(vsrc0 + (size_t)(T) * 64), \
            (__attribute__((address_space(3))) void*)(&Vs[BUF][doff0]), 16, 0, 0);     \
        __builtin_amdgcn_global_load_lds(                                              \
            (const __attribute__((address_space(1))) void*)(vsrc1 + (size_t)(T) * 64), \
            (__attribute__((address_space(3))) void*)(&Vs[BUF][doff1]), 16, 0, 0);     \
    } while (0)

    bf16x8 bqA0, bqA1, bqB0, bqB1;
    {
        const u16* qpA = qmat + (size_t)(qbA + lr) * 3072 + lg * 8;
        bqA0 = *(const bf16x8*)qpA;
        bqA1 = *(const bf16x8*)(qpA + 32);
        const u16* qpB = qmat + (size_t)(qbB + lr) * 3072 + lg * 8;
        bqB0 = *(const bf16x8*)qpB;
        bqB1 = *(const bf16x8*)(qpB + 32);
    }
    // dq_c = (dq*rate + ln8)*log2e = dq*c1 + 3
    const float dq_cA = (float)db[qbA + lr] * c1 + 3.0f;
    const float dq_cB = (float)db[qbB + lr] * c1 + 3.0f;

    float lA = 0.f, lB = 0.f;
    f32x4 accA[4] = {};
    f32x4 accB[4] = {};

    const int STEP = (NS == 2) ? 2 : 1;
    const int nkt = (NS == 2) ? (((31 - j - s) >> 1) + 1) : (32 - j);
    STAGE(s, 0);
    for (int it = 0; it < nkt; ++it) {
        const int kt = s + it * STEP;
        const int cur = it & 1;
        if (it + 1 < nkt) {
            STAGE(kt + STEP, cur ^ 1);
            asm volatile("s_waitcnt vmcnt(4)" ::: "memory");
        } else {
            asm volatile("s_waitcnt vmcnt(0)" ::: "memory");
        }
        __builtin_amdgcn_s_barrier();
        const int* dbk = db + kt * 64;
        attn_tile(Ks[cur], Vs[cur], Plds[w], dbk, bqB0, bqB1, dq_cB, c1, w * 16 + lr,
                  kt == qtB, lB, accB, lr, lg);
        if (kt <= j)
            attn_tile(Ks[cur], Vs[cur], Plds[w], dbk, bqA0, bqA1, dq_cA, c1, w * 16 + lr,
                      kt == j, lA, accA, lr, lg);
        __builtin_amdgcn_s_barrier();
    }
#undef STAGE

#pragma unroll
    for (int t = 0; t < 2; ++t) {
        float lp = t ? lA : lB;
        f32x4* acc = t ? accA : accB;
        const int qt = t ? j : qtB;
        float l_full = lp + __shfl_xor(lp, 16);
        l_full += __shfl_xor(l_full, 32);
        if (NS == 1) {
            float inv_[4];
#pragma unroll
            for (int r = 0; r < 4; ++r) inv_[r] = 1.0f / __shfl(l_full, lg * 4 + r);
#pragma unroll
            for (int c = 0; c < 4; ++c)
#pragma unroll
                for (int r = 0; r < 4; ++r) {
                    const int qg = qt * 64 + w * 16 + lg * 4 + r;
                    outp[(size_t)(b * 2048 + qg) * 1024 + h * 64 + c * 16 + lr] =
                        f2bf(acc[c][r] * inv_[r]);
                }
        } else {
            u16* nbase = outp + (((size_t)s * 32 + bh) * 32 + qt) * 4096;
#pragma unroll
            for (int c = 0; c < 4; ++c)
#pragma unroll
                for (int r = 0; r < 4; ++r)
                    nbase[(w * 16 + lg * 4 + r) * 64 + c * 16 + lr] = f2bf(acc[c][r]);
            if (lg == 0)
                l_out[((size_t)s * 32 + bh) * 32 * 64 + qt * 64 + w * 16 + lr] = l_full;
        }
    }
}

// ---------------- combine: attb = (num0+num1)/(l0+l1) ------------------------------
__global__ __launch_bounds__(256) void attn_combine_k(const u16* __restrict__ num,
                                                      const float* __restrict__ lbuf,
                                                      u16* __restrict__ attb) {
    int idx = blockIdx.x * 256 + threadIdx.x;  // 1,048,576 total
    int hd4 = idx & 15;
    int row = (idx >> 4) & 63;
    int qtbh = idx >> 10;  // bh*32 + qt
    int qt = qtbh & 31, bh = qtbh >> 5;
    const size_t SPL = (size_t)32 * 32 * 64 * 64;
    size_t nidx = ((size_t)qtbh * 64 + row) * 64 + hd4 * 4;
    uint2 a = *(const uint2*)(num + nidx);
    uint2 bb = *(const uint2*)(num + SPL + nidx);
    float l = lbuf[qtbh * 64 + row] + lbuf[32 * 32 * 64 + qtbh * 64 + row];
    float invl = 1.0f / l;
    float s0 = (bf2f((u16)a.x) + bf2f((u16)bb.x)) * invl;
    float s1 = (bf2f((u16)(a.x >> 16)) + bf2f((u16)(bb.x >> 16))) * invl;
    float s2 = (bf2f((u16)a.y) + bf2f((u16)bb.y)) * invl;
    float s3 = (bf2f((u16)(a.y >> 16)) + bf2f((u16)(bb.y >> 16))) * invl;
    int b = bh >> 4, h = bh & 15;
    int m = b * 2048 + qt * 64 + row;
    int col = h * 64 + hd4 * 4;
    uint2 o;
    o.x = (unsigned)f2bf(s0) | ((unsigned)f2bf(s1) << 16);
    o.y = (unsigned)f2bf(s2) | ((unsigned)f2bf(s3) << 16);
    *(uint2*)(attb + (size_t)m * 1024 + col) = o;
}

// ---------------- launch -----------------------------------------------------------
extern "C" void kernel_launch(void* const* d_in, const int* in_sizes, int n_in,
                              void* d_out, int out_size, void* d_ws, size_t ws_size,
                              hipStream_t stream) {
    const float* x = (const float*)d_in[0];
    const float* Wq = (const float*)d_in[1];
    const float* bq = (const float*)d_in[2];
    const float* Wk = (const float*)d_in[3];
    const float* bk = (const float*)d_in[4];
    const float* Wv = (const float*)d_in[5];
    const float* bv = (const float*)d_in[6];
    const float* Wo = (const float*)d_in[7];
    const float* bo = (const float*)d_in[8];
    const float* decay = (const float*)d_in[9];
    const int* days = (const int*)d_in[11];
    float* out = (float*)d_out;

    char* ws = (char*)d_ws;
    u16* xb = (u16*)(ws);                   //  8 MB: x bf16 [4096][1024]
    u16* wqkv = (u16*)(ws + 8388608);       //  6 MB: [Wq;Wk;Wv] bf16 [3072][1024]
    u16* wo = (u16*)(ws + 14680064);        //  2 MB: Wo bf16 [1024][1024]
    u16* qkvb = (u16*)(ws + 16777216);      // 24 MB: qkv bf16 [4096][3072]
    u16* vtb = (u16*)(ws + 41943040);       //  8 MB: Vt bf16 [32][64][2048]
    u16* attb = (u16*)(ws + 50331648);      //  8 MB: attn out bf16 [4096][1024]
    u16* numb = (u16*)(ws + 58720256);      // 16 MB: partial numerators bf16 [2][...]
    float* lbuf = (float*)(ws + 75497472);  // 0.5 MB: partial l fp32 [2][32][32][64]
    const size_t WS_NEED = 76021760;

    f32_to_bf16_k<<<4096, 256, 0, stream>>>(x, xb);
    f32_to_bf16_k<<<1024, 256, 0, stream>>>(Wq, wqkv);
    f32_to_bf16_k<<<1024, 256, 0, stream>>>(Wk, wqkv + 1048576);
    f32_to_bf16_k<<<1024, 256, 0, stream>>>(Wv, wqkv + 2097152);
    f32_to_bf16_k<<<1024, 256, 0, stream>>>(Wo, wo);

    gemm_bt<0><<<768, 256, 0, stream>>>(xb, wqkv, bq, bk, bv, days, qkvb, nullptr,
                                        4096, 3072, 1024);
    v_transpose_k<<<1024, 256, 0, stream>>>(qkvb, vtb);
    if (ws_size >= WS_NEED) {
        attn_k<2><<<1024, 256, 0, stream>>>(qkvb, vtb, days, decay, numb, lbuf);
        attn_combine_k<<<4096, 256, 0, stream>>>(numb, lbuf, attb);
    } else {
        attn_k<1><<<512, 256, 0, stream>>>(qkvb, vtb, days, decay, attb, nullptr);
    }
    gemm_bt<1><<<256, 256, 0, stream>>>(attb, wo, bo, nullptr, nullptr, days, nullptr,
                                        out, 4096, 1024, 1024);
}